// Round 2
// baseline (402.201 us; speedup 1.0000x reference)
//
#include <hip/hip_runtime.h>
#include <math.h>

#define NOISE 1e-12f

__device__ __forceinline__ float2 cmul(float2 a, float2 b) {
    return make_float2(a.x*b.x - a.y*b.y, a.x*b.y + a.y*b.x);
}
// conj(a)*b
__device__ __forceinline__ float2 cconjmul(float2 a, float2 b) {
    return make_float2(a.x*b.x + a.y*b.y, a.x*b.y - a.y*b.x);
}
// a*conj(b)
__device__ __forceinline__ float2 cmulconj(float2 a, float2 b) {
    return make_float2(a.x*b.x + a.y*b.y, a.y*b.x - a.x*b.y);
}
__device__ __forceinline__ float2 cadd(float2 a, float2 b){ return make_float2(a.x+b.x, a.y+b.y); }
__device__ __forceinline__ float2 csub(float2 a, float2 b){ return make_float2(a.x-b.x, a.y-b.y); }
__device__ __forceinline__ float2 cscale(float s, float2 a){ return make_float2(s*a.x, s*a.y); }

// complex accumulate: P[o]+iP[o+1] += (gr+i gi)*(thr+i thi) * (ur+i ui)
#define ACC(P, GR, GI, THR, THI, UR, UI, o) { \
    float vr = (GR)*(THR) - (GI)*(THI);       \
    float vi = (GR)*(THI) + (GI)*(THR);       \
    P[o]   += vr*(UR) - vi*(UI);              \
    P[o+1] += vr*(UI) + vi*(UR); }

// one wave handles 4 batch elements: 2 outer iterations x 2 concurrent (ILP)
__global__ __launch_bounds__(256) void rate_kernel(
    const float* __restrict__ t1,
    const float* __restrict__ G1r, const float* __restrict__ G1i,
    const float* __restrict__ G2r, const float* __restrict__ G2i,
    const float* __restrict__ Ur,  const float* __restrict__ Ui,
    float* __restrict__ partial)
{
    __shared__ float2 ent[4][4][16];   // [wave][ib][entry]
    __shared__ float wsum[4];
    const int wave = threadIdx.x >> 6;
    const int lane = threadIdx.x & 63;
    const int t  = lane & 7;     // output column of phi
    const int k0 = lane >> 3;    // k-strip (k = 8j + k0), reused as entry-octet id
    const int e8 = k0;
    const int nn = (e8 >> 1) & 1;
    const int rr = e8 & 1;

    for (int it = 0; it < 2; ++it) {
        const long b0 = (long)blockIdx.x * 16 + (long)wave * 4 + it * 2;
        const float* tA   = t1  + b0 * 264;  const float* tB   = tA   + 264;
        const float* g1rA = G1r + b0 * 200;  const float* g1rB = g1rA + 200;
        const float* g1iA = G1i + b0 * 200;  const float* g1iB = g1iA + 200;
        const float* g2rA = G2r + b0 * 200;  const float* g2rB = g2rA + 200;
        const float* g2iA = G2i + b0 * 200;  const float* g2iB = g2iA + 200;
        const float* urA  = Ur  + b0 * 800;  const float* urB  = urA  + 800;
        const float* uiA  = Ui  + b0 * 800;  const float* uiB  = uiA  + 800;

        // phi partials: [0,1]=phi1 n0 re/im, [2,3]=phi1 n1, [4,5]=phi2 n0, [6,7]=phi2 n1
        float pA[8] = {0,0,0,0,0,0,0,0};
        float pB[8] = {0,0,0,0,0,0,0,0};

        #pragma unroll 2
        for (int j = 0; j < 12; ++j) {
            const int k = 8*j + k0;
            const int f = k*8 + t;  // = 64j + lane: coalesced
            float thrA = tA[k], thiA = tA[100+k];
            float thrB = tB[k], thiB = tB[100+k];
            float uRA = urA[f], uIA = uiA[f];
            float uRB = urB[f], uIB = uiB[f];
            ACC(pA, g1rA[k],     g1iA[k],     thrA, thiA, uRA, uIA, 0);
            ACC(pB, g1rB[k],     g1iB[k],     thrB, thiB, uRB, uIB, 0);
            ACC(pA, g1rA[100+k], g1iA[100+k], thrA, thiA, uRA, uIA, 2);
            ACC(pB, g1rB[100+k], g1iB[100+k], thrB, thiB, uRB, uIB, 2);
            ACC(pA, g2rA[k],     g2iA[k],     thrA, thiA, uRA, uIA, 4);
            ACC(pB, g2rB[k],     g2iB[k],     thrB, thiB, uRB, uIB, 4);
            ACC(pA, g2rA[100+k], g2iA[100+k], thrA, thiA, uRA, uIA, 6);
            ACC(pB, g2rB[100+k], g2iB[100+k], thrB, thiB, uRB, uIB, 6);
        }
        { // j = 12 tail: k = 96 + k0 valid only for k0 < 4
            const int k = 96 + k0;
            if (k < 100) {
                const int f = k*8 + t;
                float thrA = tA[k], thiA = tA[100+k];
                float thrB = tB[k], thiB = tB[100+k];
                float uRA = urA[f], uIA = uiA[f];
                float uRB = urB[f], uIB = uiB[f];
                ACC(pA, g1rA[k],     g1iA[k],     thrA, thiA, uRA, uIA, 0);
                ACC(pB, g1rB[k],     g1iB[k],     thrB, thiB, uRB, uIB, 0);
                ACC(pA, g1rA[100+k], g1iA[100+k], thrA, thiA, uRA, uIA, 2);
                ACC(pB, g1rB[100+k], g1iB[100+k], thrB, thiB, uRB, uIB, 2);
                ACC(pA, g2rA[k],     g2iA[k],     thrA, thiA, uRA, uIA, 4);
                ACC(pB, g2rB[k],     g2iB[k],     thrB, thiB, uRB, uIB, 4);
                ACC(pA, g2rA[100+k], g2iA[100+k], thrA, thiA, uRA, uIA, 6);
                ACC(pB, g2rB[100+k], g2iB[100+k], thrB, thiB, uRB, uIB, 6);
            }
        }

        // reduce over the 8 k-strips (lanes differing in bits 3..5), both b interleaved
        #pragma unroll
        for (int s = 8; s < 64; s <<= 1) {
            #pragma unroll
            for (int q = 0; q < 8; ++q) {
                pA[q] += __shfl_xor(pA[q], s);
                pB[q] += __shfl_xor(pB[q], s);
            }
        }

        // ---- F norms: scale_h = sqrt(2 / sum|F_h|^2) ----
        float s1A, s2A, s1B, s2B;
        {
            int idx = lane & 15;
            int sel = (lane >> 4) & 1;
            float frA = tA[200 + sel*32 + idx], fiA = tA[216 + sel*32 + idx];
            float frB = tB[200 + sel*32 + idx], fiB = tB[216 + sel*32 + idx];
            float mA = frA*frA + fiA*fiA;
            float mB = frB*frB + fiB*fiB;
            #pragma unroll
            for (int s = 1; s < 16; s <<= 1) { mA += __shfl_xor(mA, s); mB += __shfl_xor(mB, s); }
            float oA = __shfl_xor(mA, 16);
            float oB = __shfl_xor(mB, 16);
            float n1A = sel ? oA : mA, n2A = sel ? mA : oA;
            float n1B = sel ? oB : mB, n2B = sel ? mB : oB;
            s1A = sqrtf(2.0f / n1A); s2A = sqrtf(2.0f / n2A);
            s1B = sqrtf(2.0f / n1B); s2B = sqrtf(2.0f / n2B);
        }

        // ---- A/C entries: ent[ib][0..7] = A,C for R1 (phi1,F1,F2); [8..15] for R2 ----
        {
            int jf = t*2 + rr;
            float2 f1A = make_float2(tA[200 + jf], tA[216 + jf]);
            float2 f2A = make_float2(tA[232 + jf], tA[248 + jf]);
            float2 f1B = make_float2(tB[200 + jf], tB[216 + jf]);
            float2 f2B = make_float2(tB[232 + jf], tB[248 + jf]);
            float2 phi1A = nn ? make_float2(pA[2],pA[3]) : make_float2(pA[0],pA[1]);
            float2 phi2A = nn ? make_float2(pA[6],pA[7]) : make_float2(pA[4],pA[5]);
            float2 phi1B = nn ? make_float2(pB[2],pB[3]) : make_float2(pB[0],pB[1]);
            float2 phi2B = nn ? make_float2(pB[6],pB[7]) : make_float2(pB[4],pB[5]);
            bool lo = (e8 < 4);
            float2 E0A = cmul(phi1A, lo ? f1A : f2A);
            float2 E1A = cmul(phi2A, lo ? f2A : f1A);
            float2 E0B = cmul(phi1B, lo ? f1B : f2B);
            float2 E1B = cmul(phi2B, lo ? f2B : f1B);
            #pragma unroll
            for (int s = 1; s < 8; s <<= 1) {
                E0A.x += __shfl_xor(E0A.x, s); E0A.y += __shfl_xor(E0A.y, s);
                E1A.x += __shfl_xor(E1A.x, s); E1A.y += __shfl_xor(E1A.y, s);
                E0B.x += __shfl_xor(E0B.x, s); E0B.y += __shfl_xor(E0B.y, s);
                E1B.x += __shfl_xor(E1B.x, s); E1B.y += __shfl_xor(E1B.y, s);
            }
            if (t == 0) {
                ent[wave][it*2    ][e8]     = cscale(lo ? s1A : s2A, E0A);
                ent[wave][it*2    ][e8 + 8] = cscale(lo ? s2A : s1A, E1A);
                ent[wave][it*2 + 1][e8]     = cscale(lo ? s1B : s2B, E0B);
                ent[wave][it*2 + 1][e8 + 8] = cscale(lo ? s2B : s1B, E1B);
            }
        }
    }
    __builtin_amdgcn_wave_barrier();

    // ---- batched 2x2 complex rate: lanes 0..7 -> (ib = lane>>1, R1/R2 = lane&1) ----
    float negR = 0.0f;
    if (lane < 8) {
        const float2* e = &ent[wave][lane >> 1][(lane & 1) * 8];
        float2 A00=e[0], A01=e[1], A10=e[2], A11=e[3];
        float2 C00=e[4], C01=e[5], C10=e[6], C11=e[7];
        float mu00 = C00.x*C00.x + C00.y*C00.y + C01.x*C01.x + C01.y*C01.y + NOISE;
        float mu11 = C10.x*C10.x + C10.y*C10.y + C11.x*C11.x + C11.y*C11.y + NOISE;
        float2 mu01 = cadd(cmulconj(C00, C10), cmulconj(C01, C11));
        mu01.x += NOISE;
        float det = mu00*mu11 - (mu01.x*mu01.x + mu01.y*mu01.y);
        float inv = 1.0f / det;
        float2 mu01c = make_float2(mu01.x, -mu01.y);
        float2 X00 = cscale(inv, csub(cscale(mu11, A00), cmul(mu01,  A10)));
        float2 X01 = cscale(inv, csub(cscale(mu11, A01), cmul(mu01,  A11)));
        float2 X10 = cscale(inv, csub(cscale(mu00, A10), cmul(mu01c, A00)));
        float2 X11 = cscale(inv, csub(cscale(mu00, A11), cmul(mu01c, A01)));
        float2 I00 = cadd(cconjmul(A00, X00), cconjmul(A10, X10));
        float2 I01 = cadd(cconjmul(A00, X01), cconjmul(A10, X11));
        float2 I10 = cadd(cconjmul(A01, X00), cconjmul(A11, X10));
        float2 I11 = cadd(cconjmul(A01, X01), cconjmul(A11, X11));
        I00.x += 1.0f; I01.x += 1.0f; I10.x += 1.0f; I11.x += 1.0f;
        float2 dT = csub(cmul(I00, I11), cmul(I01, I10));
        negR = -0.5f * logf(dT.x*dT.x + dT.y*dT.y);  // -Re(log z) = -ln|z|
    }
    // pairwise max over (R1,R2), then sum the 4 batch elements
    float m = fmaxf(negR, __shfl_xor(negR, 1));
    m += __shfl_xor(m, 2);
    m += __shfl_xor(m, 4);
    if (lane == 0) wsum[wave] = m;

    __syncthreads();
    if (threadIdx.x == 0)
        partial[blockIdx.x] = (wsum[0] + wsum[1]) + (wsum[2] + wsum[3]);
}

__global__ __launch_bounds__(256) void reduce_kernel(
    const float* __restrict__ partial, int n, float invB, float* __restrict__ out)
{
    __shared__ float sd[256];
    float s = 0.0f;
    for (int i = threadIdx.x; i < n; i += 256) s += partial[i];
    sd[threadIdx.x] = s;
    __syncthreads();
    for (int o = 128; o > 0; o >>= 1) {
        if ((int)threadIdx.x < o) sd[threadIdx.x] += sd[threadIdx.x + o];
        __syncthreads();
    }
    if (threadIdx.x == 0) out[0] = sd[0] * invB;
}

extern "C" void kernel_launch(void* const* d_in, const int* in_sizes, int n_in,
                              void* d_out, int out_size, void* d_ws, size_t ws_size,
                              hipStream_t stream) {
    const float* t1  = (const float*)d_in[0];
    const float* G1r = (const float*)d_in[1];
    const float* G1i = (const float*)d_in[2];
    const float* G2r = (const float*)d_in[3];
    const float* G2i = (const float*)d_in[4];
    const float* Ur  = (const float*)d_in[5];
    const float* Ui  = (const float*)d_in[6];

    const int B = in_sizes[0] / 264;        // 65536
    const int nblocks = B / 16;             // 16 batch elements per block
    float* partial = (float*)d_ws;          // nblocks floats

    rate_kernel<<<nblocks, 256, 0, stream>>>(t1, G1r, G1i, G2r, G2i, Ur, Ui, partial);
    reduce_kernel<<<1, 256, 0, stream>>>(partial, nblocks, 1.0f / (float)B, (float*)d_out);
}

// Round 3
// 247.375 us; speedup vs baseline: 1.6259x; 1.6259x over previous
//
#include <hip/hip_runtime.h>
#include <math.h>

#define NOISE 1e-12f

__device__ __forceinline__ float2 cmul(float2 a, float2 b) {
    return make_float2(a.x*b.x - a.y*b.y, a.x*b.y + a.y*b.x);
}
// conj(a)*b
__device__ __forceinline__ float2 cconjmul(float2 a, float2 b) {
    return make_float2(a.x*b.x + a.y*b.y, a.x*b.y - a.y*b.x);
}
// a*conj(b)
__device__ __forceinline__ float2 cmulconj(float2 a, float2 b) {
    return make_float2(a.x*b.x + a.y*b.y, a.y*b.x - a.x*b.y);
}
__device__ __forceinline__ float2 cadd(float2 a, float2 b){ return make_float2(a.x+b.x, a.y+b.y); }
__device__ __forceinline__ float2 csub(float2 a, float2 b){ return make_float2(a.x-b.x, a.y-b.y); }
__device__ __forceinline__ float2 cscale(float s, float2 a){ return make_float2(s*a.x, s*a.y); }

// body for one k-strip element: w = theta*u, then 4 complex FMAs p += G*w
#define JBODY(k, f) {                                            \
    float thr = tb[(k)], thi = tb[100+(k)];                      \
    float ur  = urb[(f)], ui  = uib[(f)];                        \
    float wr = thr*ur - thi*ui, wi = thr*ui + thi*ur;            \
    p[0] += g1rb[(k)]*wr     - g1ib[(k)]*wi;                     \
    p[1] += g1rb[(k)]*wi     + g1ib[(k)]*wr;                     \
    p[2] += g1rb[100+(k)]*wr - g1ib[100+(k)]*wi;                 \
    p[3] += g1rb[100+(k)]*wi + g1ib[100+(k)]*wr;                 \
    p[4] += g2rb[(k)]*wr     - g2ib[(k)]*wi;                     \
    p[5] += g2rb[(k)]*wi     + g2ib[(k)]*wr;                     \
    p[6] += g2rb[100+(k)]*wr - g2ib[100+(k)]*wi;                 \
    p[7] += g2rb[100+(k)]*wi + g2ib[100+(k)]*wr; }

// one wave per batch element iteration; 4 waves/block; 4 iterations -> 16 b per block
__global__ __launch_bounds__(256) void rate_kernel(
    const float* __restrict__ t1,
    const float* __restrict__ G1r, const float* __restrict__ G1i,
    const float* __restrict__ G2r, const float* __restrict__ G2i,
    const float* __restrict__ Ur,  const float* __restrict__ Ui,
    float* __restrict__ partial)
{
    __shared__ float2 ent[4][4][16];   // [wave][it][entry]
    __shared__ float wsum[4];
    const int wave = threadIdx.x >> 6;
    const int lane = threadIdx.x & 63;
    const int t  = lane & 7;     // output column of phi
    const int k0 = lane >> 3;    // k-strip (k = 8j + k0), reused as entry-octet id
    const int e8 = k0;
    const int nn = (e8 >> 1) & 1;
    const int rr = e8 & 1;

    for (int it = 0; it < 4; ++it) {
        const long b = (long)blockIdx.x * 16 + (long)wave * 4 + it;
        const float* tb   = t1  + b * 264;
        const float* g1rb = G1r + b * 200;
        const float* g1ib = G1i + b * 200;
        const float* g2rb = G2r + b * 200;
        const float* g2ib = G2i + b * 200;
        const float* urb  = Ur  + b * 800;
        const float* uib  = Ui  + b * 800;

        // phi partials: [0,1]=phi1 n0 re/im, [2,3]=phi1 n1, [4,5]=phi2 n0, [6,7]=phi2 n1
        float p[8] = {0,0,0,0,0,0,0,0};

        // 12 uniform strips, fully unrolled -> all offsets compile-time imm
        #pragma unroll
        for (int j = 0; j < 12; ++j) {
            JBODY(8*j + k0, 64*j + lane);
        }
        // tail strip: k = 96 + k0, valid only for k0 < 4 (masked; avoids OOB U read)
        if (k0 < 4) {
            JBODY(96 + k0, 768 + lane);
        }

        // reduce over the 8 k-strips (lanes differing in bits 3..5)
        #pragma unroll
        for (int s = 8; s < 64; s <<= 1) {
            #pragma unroll
            for (int q = 0; q < 8; ++q) p[q] += __shfl_xor(p[q], s);
        }
        // now every lane holds full phi1[n][t], phi2[n][t] for t = lane&7

        // ---- F norms: scale_h = sqrt(2 / sum|F_h|^2) ----
        float s1, s2;
        {
            int idx = lane & 15;
            int sel = (lane >> 4) & 1;
            float fr = t1[b*264 + 200 + sel*32 + idx];
            float fi = t1[b*264 + 216 + sel*32 + idx];
            float m = fr*fr + fi*fi;
            #pragma unroll
            for (int s = 1; s < 16; s <<= 1) m += __shfl_xor(m, s);
            float other = __shfl_xor(m, 16);
            float nrm1 = sel ? other : m;
            float nrm2 = sel ? m : other;
            s1 = sqrtf(2.0f / nrm1);
            s2 = sqrtf(2.0f / nrm2);
        }

        // ---- A/C entries: e = mat*4 + n*2 + r ----
        // ent[it][0..7] = {A,C} for R1 (phi1 with F1 sig, F2 intf); [8..15] for R2
        {
            int jf = t*2 + rr;
            float2 f1 = make_float2(tb[200 + jf], tb[216 + jf]);
            float2 f2 = make_float2(tb[232 + jf], tb[248 + jf]);
            float2 phi1n = nn ? make_float2(p[2],p[3]) : make_float2(p[0],p[1]);
            float2 phi2n = nn ? make_float2(p[6],p[7]) : make_float2(p[4],p[5]);
            bool lo = (e8 < 4);
            float2 E0 = cmul(phi1n, lo ? f1 : f2);
            float2 E1 = cmul(phi2n, lo ? f2 : f1);
            #pragma unroll
            for (int s = 1; s < 8; s <<= 1) {
                E0.x += __shfl_xor(E0.x, s); E0.y += __shfl_xor(E0.y, s);
                E1.x += __shfl_xor(E1.x, s); E1.y += __shfl_xor(E1.y, s);
            }
            if (t == 0) {
                ent[wave][it][e8]     = cscale(lo ? s1 : s2, E0);
                ent[wave][it][e8 + 8] = cscale(lo ? s2 : s1, E1);
            }
        }
    }
    __builtin_amdgcn_wave_barrier();

    // ---- batched 2x2 complex rate: lanes 0..7 -> (it = lane>>1, R1/R2 = lane&1) ----
    float negR = 0.0f;
    if (lane < 8) {
        const float2* e = &ent[wave][lane >> 1][(lane & 1) * 8];
        float2 A00=e[0], A01=e[1], A10=e[2], A11=e[3];
        float2 C00=e[4], C01=e[5], C10=e[6], C11=e[7];
        float mu00 = C00.x*C00.x + C00.y*C00.y + C01.x*C01.x + C01.y*C01.y + NOISE;
        float mu11 = C10.x*C10.x + C10.y*C10.y + C11.x*C11.x + C11.y*C11.y + NOISE;
        float2 mu01 = cadd(cmulconj(C00, C10), cmulconj(C01, C11));
        mu01.x += NOISE;
        float det = mu00*mu11 - (mu01.x*mu01.x + mu01.y*mu01.y);
        float inv = 1.0f / det;
        float2 mu01c = make_float2(mu01.x, -mu01.y);
        float2 X00 = cscale(inv, csub(cscale(mu11, A00), cmul(mu01,  A10)));
        float2 X01 = cscale(inv, csub(cscale(mu11, A01), cmul(mu01,  A11)));
        float2 X10 = cscale(inv, csub(cscale(mu00, A10), cmul(mu01c, A00)));
        float2 X11 = cscale(inv, csub(cscale(mu00, A11), cmul(mu01c, A01)));
        float2 I00 = cadd(cconjmul(A00, X00), cconjmul(A10, X10));
        float2 I01 = cadd(cconjmul(A00, X01), cconjmul(A10, X11));
        float2 I10 = cadd(cconjmul(A01, X00), cconjmul(A11, X10));
        float2 I11 = cadd(cconjmul(A01, X01), cconjmul(A11, X11));
        I00.x += 1.0f; I01.x += 1.0f; I10.x += 1.0f; I11.x += 1.0f;
        float2 dT = csub(cmul(I00, I11), cmul(I01, I10));
        negR = -0.5f * logf(dT.x*dT.x + dT.y*dT.y);  // -Re(log z) = -ln|z|
    }
    // pairwise max over (R1,R2), then sum the 4 batch elements
    float m = fmaxf(negR, __shfl_xor(negR, 1));
    m += __shfl_xor(m, 2);
    m += __shfl_xor(m, 4);
    if (lane == 0) wsum[wave] = m;

    __syncthreads();
    if (threadIdx.x == 0)
        partial[blockIdx.x] = (wsum[0] + wsum[1]) + (wsum[2] + wsum[3]);
}

__global__ __launch_bounds__(256) void reduce_kernel(
    const float* __restrict__ partial, int n, float invB, float* __restrict__ out)
{
    __shared__ float sd[256];
    float s = 0.0f;
    for (int i = threadIdx.x; i < n; i += 256) s += partial[i];
    sd[threadIdx.x] = s;
    __syncthreads();
    for (int o = 128; o > 0; o >>= 1) {
        if ((int)threadIdx.x < o) sd[threadIdx.x] += sd[threadIdx.x + o];
        __syncthreads();
    }
    if (threadIdx.x == 0) out[0] = sd[0] * invB;
}

extern "C" void kernel_launch(void* const* d_in, const int* in_sizes, int n_in,
                              void* d_out, int out_size, void* d_ws, size_t ws_size,
                              hipStream_t stream) {
    const float* t1  = (const float*)d_in[0];
    const float* G1r = (const float*)d_in[1];
    const float* G1i = (const float*)d_in[2];
    const float* G2r = (const float*)d_in[3];
    const float* G2i = (const float*)d_in[4];
    const float* Ur  = (const float*)d_in[5];
    const float* Ui  = (const float*)d_in[6];

    const int B = in_sizes[0] / 264;        // 65536
    const int nblocks = B / 16;             // 16 batch elements per block
    float* partial = (float*)d_ws;          // nblocks floats

    rate_kernel<<<nblocks, 256, 0, stream>>>(t1, G1r, G1i, G2r, G2i, Ur, Ui, partial);
    reduce_kernel<<<1, 256, 0, stream>>>(partial, nblocks, 1.0f / (float)B, (float*)d_out);
}

// Round 5
// 181.356 us; speedup vs baseline: 2.2177x; 1.3640x over previous
//
#include <hip/hip_runtime.h>
#include <math.h>

#define NOISE 1e-12f

__device__ __forceinline__ float2 cmul(float2 a, float2 b) {
    return make_float2(a.x*b.x - a.y*b.y, a.x*b.y + a.y*b.x);
}
// conj(a)*b
__device__ __forceinline__ float2 cconjmul(float2 a, float2 b) {
    return make_float2(a.x*b.x + a.y*b.y, a.x*b.y - a.y*b.x);
}
// a*conj(b)
__device__ __forceinline__ float2 cmulconj(float2 a, float2 b) {
    return make_float2(a.x*b.x + a.y*b.y, a.y*b.x - a.x*b.y);
}
__device__ __forceinline__ float2 cadd(float2 a, float2 b){ return make_float2(a.x+b.x, a.y+b.y); }
__device__ __forceinline__ float2 csub(float2 a, float2 b){ return make_float2(a.x-b.x, a.y-b.y); }
__device__ __forceinline__ float2 cscale(float s, float2 a){ return make_float2(s*a.x, s*a.y); }

// factored body: w = theta[k]*U[k][t] (4 ops), then p += G*w for 4 G rows (16 fma)
#define JBODY(k, f) {                                            \
    float thr = tb[(k)], thi = tb[100+(k)];                      \
    float ur  = urb[(f)], ui  = uib[(f)];                        \
    float wr = thr*ur - thi*ui, wi = thr*ui + thi*ur;            \
    p[0] += g1rb[(k)]*wr     - g1ib[(k)]*wi;                     \
    p[1] += g1rb[(k)]*wi     + g1ib[(k)]*wr;                     \
    p[2] += g1rb[100+(k)]*wr - g1ib[100+(k)]*wi;                 \
    p[3] += g1rb[100+(k)]*wi + g1ib[100+(k)]*wr;                 \
    p[4] += g2rb[(k)]*wr     - g2ib[(k)]*wi;                     \
    p[5] += g2rb[(k)]*wi     + g2ib[(k)]*wr;                     \
    p[6] += g2rb[100+(k)]*wr - g2ib[100+(k)]*wi;                 \
    p[7] += g2rb[100+(k)]*wi + g2ib[100+(k)]*wr; }

// one wave per batch element iteration; 4 waves/block; 4 iterations -> 16 b per block
__global__ __launch_bounds__(256) void rate_kernel(
    const float* __restrict__ t1,
    const float* __restrict__ G1r, const float* __restrict__ G1i,
    const float* __restrict__ G2r, const float* __restrict__ G2i,
    const float* __restrict__ Ur,  const float* __restrict__ Ui,
    float* __restrict__ partial)
{
    __shared__ float2 ent[4][4][16];   // [wave][it][entry]
    __shared__ float wsum[4];
    const int wave = threadIdx.x >> 6;
    const int lane = threadIdx.x & 63;
    const int t  = lane & 7;     // output column of phi
    const int k0 = lane >> 3;    // k-strip (k = 8j + k0), reused as entry-octet id
    const int e8 = k0;
    const int nn = (e8 >> 1) & 1;   // = lane bit 4
    const int rr = e8 & 1;

    for (int it = 0; it < 4; ++it) {
        const long b = (long)blockIdx.x * 16 + (long)wave * 4 + it;
        const float* tb   = t1  + b * 264;
        const float* g1rb = G1r + b * 200;
        const float* g1ib = G1i + b * 200;
        const float* g2rb = G2r + b * 200;
        const float* g2ib = G2i + b * 200;
        const float* urb  = Ur  + b * 800;
        const float* uib  = Ui  + b * 800;

        // phi partials: [0,1]=phi1 n0 re/im, [2,3]=phi1 n1, [4,5]=phi2 n0, [6,7]=phi2 n1
        float p[8] = {0,0,0,0,0,0,0,0};

        #pragma unroll 1   // keep the rolled R1-style schedule (VGPR ~44, occ 50%)
        for (int j = 0; j < 12; ++j) {
            JBODY(8*j + k0, 64*j + lane);
        }
        // tail strip: k = 96 + k0, valid only for k0 < 4 (masked; avoids OOB U read)
        if (k0 < 4) {
            JBODY(96 + k0, 768 + lane);
        }

        // reduce over the 8 k-strips (lane bits 3..5).
        // Stage bits 3 and 5 for all 8 partials; for bit 4, each lane keeps the
        // n it needs (nn) and SENDS the other n (what its xor-16 partner needs):
        // exchange-then-add. (R4 bug: selecting before the exchange mixed n0/n1.)
        #pragma unroll
        for (int q = 0; q < 8; ++q) {
            p[q] += __shfl_xor(p[q], 8);
            p[q] += __shfl_xor(p[q], 32);
        }
        float4 ph;  // phi1[nn].re/.im, phi2[nn].re/.im (full k-sum after exchange)
        {
            float k0r = nn ? p[2] : p[0], s0r = nn ? p[0] : p[2];
            float k0i = nn ? p[3] : p[1], s0i = nn ? p[1] : p[3];
            float k1r = nn ? p[6] : p[4], s1r = nn ? p[4] : p[6];
            float k1i = nn ? p[7] : p[5], s1i = nn ? p[5] : p[7];
            ph.x = k0r + __shfl_xor(s0r, 16);
            ph.y = k0i + __shfl_xor(s0i, 16);
            ph.z = k1r + __shfl_xor(s1r, 16);
            ph.w = k1i + __shfl_xor(s1i, 16);
        }
        // now lane holds phi1[nn][t], phi2[nn][t] fully reduced

        // ---- F norms: scale_h = sqrt(2 / sum|F_h|^2) ----
        float s1, s2;
        {
            int idx = lane & 15;
            int sel = (lane >> 4) & 1;
            float fr = tb[200 + sel*32 + idx];
            float fi = tb[216 + sel*32 + idx];
            float m = fr*fr + fi*fi;
            #pragma unroll
            for (int s = 1; s < 16; s <<= 1) m += __shfl_xor(m, s);
            float other = __shfl_xor(m, 16);
            float nrm1 = sel ? other : m;
            float nrm2 = sel ? m : other;
            s1 = sqrtf(2.0f / nrm1);
            s2 = sqrtf(2.0f / nrm2);
        }

        // ---- A/C entries: e = mat*4 + n*2 + r ----
        // ent[it][0..7] = {A,C} for R1 (phi1 with F1 sig, F2 intf); [8..15] for R2
        {
            int jf = t*2 + rr;
            float2 f1 = make_float2(tb[200 + jf], tb[216 + jf]);
            float2 f2 = make_float2(tb[232 + jf], tb[248 + jf]);
            float2 phi1n = make_float2(ph.x, ph.y);
            float2 phi2n = make_float2(ph.z, ph.w);
            bool lo = (e8 < 4);
            float2 E0 = cmul(phi1n, lo ? f1 : f2);
            float2 E1 = cmul(phi2n, lo ? f2 : f1);
            #pragma unroll
            for (int s = 1; s < 8; s <<= 1) {
                E0.x += __shfl_xor(E0.x, s); E0.y += __shfl_xor(E0.y, s);
                E1.x += __shfl_xor(E1.x, s); E1.y += __shfl_xor(E1.y, s);
            }
            if (t == 0) {
                ent[wave][it][e8]     = cscale(lo ? s1 : s2, E0);
                ent[wave][it][e8 + 8] = cscale(lo ? s2 : s1, E1);
            }
        }
    }
    __builtin_amdgcn_wave_barrier();

    // ---- batched 2x2 complex rate: lanes 0..7 -> (it = lane>>1, R1/R2 = lane&1) ----
    float negR = 0.0f;
    if (lane < 8) {
        const float2* e = &ent[wave][lane >> 1][(lane & 1) * 8];
        float2 A00=e[0], A01=e[1], A10=e[2], A11=e[3];
        float2 C00=e[4], C01=e[5], C10=e[6], C11=e[7];
        float mu00 = C00.x*C00.x + C00.y*C00.y + C01.x*C01.x + C01.y*C01.y + NOISE;
        float mu11 = C10.x*C10.x + C10.y*C10.y + C11.x*C11.x + C11.y*C11.y + NOISE;
        float2 mu01 = cadd(cmulconj(C00, C10), cmulconj(C01, C11));
        mu01.x += NOISE;
        float det = mu00*mu11 - (mu01.x*mu01.x + mu01.y*mu01.y);
        float inv = 1.0f / det;
        float2 mu01c = make_float2(mu01.x, -mu01.y);
        float2 X00 = cscale(inv, csub(cscale(mu11, A00), cmul(mu01,  A10)));
        float2 X01 = cscale(inv, csub(cscale(mu11, A01), cmul(mu01,  A11)));
        float2 X10 = cscale(inv, csub(cscale(mu00, A10), cmul(mu01c, A00)));
        float2 X11 = cscale(inv, csub(cscale(mu00, A11), cmul(mu01c, A01)));
        float2 I00 = cadd(cconjmul(A00, X00), cconjmul(A10, X10));
        float2 I01 = cadd(cconjmul(A00, X01), cconjmul(A10, X11));
        float2 I10 = cadd(cconjmul(A01, X00), cconjmul(A11, X10));
        float2 I11 = cadd(cconjmul(A01, X01), cconjmul(A11, X11));
        I00.x += 1.0f; I01.x += 1.0f; I10.x += 1.0f; I11.x += 1.0f;
        float2 dT = csub(cmul(I00, I11), cmul(I01, I10));
        negR = -0.5f * logf(dT.x*dT.x + dT.y*dT.y);  // -Re(log z) = -ln|z|
    }
    // pairwise max over (R1,R2), then sum the 4 batch elements
    float m = fmaxf(negR, __shfl_xor(negR, 1));
    m += __shfl_xor(m, 2);
    m += __shfl_xor(m, 4);
    if (lane == 0) wsum[wave] = m;

    __syncthreads();
    if (threadIdx.x == 0)
        partial[blockIdx.x] = (wsum[0] + wsum[1]) + (wsum[2] + wsum[3]);
}

__global__ __launch_bounds__(256) void reduce_kernel(
    const float* __restrict__ partial, int n, float invB, float* __restrict__ out)
{
    __shared__ float sd[256];
    float s = 0.0f;
    for (int i = threadIdx.x; i < n; i += 256) s += partial[i];
    sd[threadIdx.x] = s;
    __syncthreads();
    for (int o = 128; o > 0; o >>= 1) {
        if ((int)threadIdx.x < o) sd[threadIdx.x] += sd[threadIdx.x + o];
        __syncthreads();
    }
    if (threadIdx.x == 0) out[0] = sd[0] * invB;
}

extern "C" void kernel_launch(void* const* d_in, const int* in_sizes, int n_in,
                              void* d_out, int out_size, void* d_ws, size_t ws_size,
                              hipStream_t stream) {
    const float* t1  = (const float*)d_in[0];
    const float* G1r = (const float*)d_in[1];
    const float* G1i = (const float*)d_in[2];
    const float* G2r = (const float*)d_in[3];
    const float* G2i = (const float*)d_in[4];
    const float* Ur  = (const float*)d_in[5];
    const float* Ui  = (const float*)d_in[6];

    const int B = in_sizes[0] / 264;        // 65536
    const int nblocks = B / 16;             // 16 batch elements per block
    float* partial = (float*)d_ws;          // nblocks floats

    rate_kernel<<<nblocks, 256, 0, stream>>>(t1, G1r, G1i, G2r, G2i, Ur, Ui, partial);
    reduce_kernel<<<1, 256, 0, stream>>>(partial, nblocks, 1.0f / (float)B, (float*)d_out);
}

// Round 6
// 165.764 us; speedup vs baseline: 2.4263x; 1.0941x over previous
//
#include <hip/hip_runtime.h>
#include <math.h>

#define NOISE 1e-12f
#define WSZ 1064   // per-wave LDS floats: theta(200) | G1(400) | G2(400) | F(64)

__device__ __forceinline__ float2 cmul(float2 a, float2 b) {
    return make_float2(a.x*b.x - a.y*b.y, a.x*b.y + a.y*b.x);
}
// conj(a)*b
__device__ __forceinline__ float2 cconjmul(float2 a, float2 b) {
    return make_float2(a.x*b.x + a.y*b.y, a.x*b.y - a.y*b.x);
}
// a*conj(b)
__device__ __forceinline__ float2 cmulconj(float2 a, float2 b) {
    return make_float2(a.x*b.x + a.y*b.y, a.y*b.x - a.x*b.y);
}
__device__ __forceinline__ float2 cadd(float2 a, float2 b){ return make_float2(a.x+b.x, a.y+b.y); }
__device__ __forceinline__ float2 csub(float2 a, float2 b){ return make_float2(a.x-b.x, a.y-b.y); }
__device__ __forceinline__ float2 cscale(float s, float2 a){ return make_float2(s*a.x, s*a.y); }

// one wave per batch element iteration; 4 waves/block; 4 iterations -> 16 b per block
__global__ __launch_bounds__(256) void rate_kernel(
    const float* __restrict__ t1,
    const float* __restrict__ G1r, const float* __restrict__ G1i,
    const float* __restrict__ G2r, const float* __restrict__ G2i,
    const float* __restrict__ Ur,  const float* __restrict__ Ui,
    float* __restrict__ partial)
{
    __shared__ float lds[4 * WSZ];     // per-wave staging buffers
    __shared__ float2 ent[4][4][16];   // [wave][it][entry]
    __shared__ float wsum[4];
    const int wave = threadIdx.x >> 6;
    const int lane = threadIdx.x & 63;
    const int t  = lane & 7;     // output column of phi
    const int k0 = lane >> 3;    // k-strip (k = 8j + k0), reused as entry-octet id
    const int e8 = k0;
    const int nn = (e8 >> 1) & 1;   // = lane bit 4
    const int rr = e8 & 1;
    float* W = lds + wave * WSZ;

    for (int it = 0; it < 4; ++it) {
        const long b = (long)blockIdx.x * 16 + (long)wave * 4 + it;
        const float* tb   = t1  + b * 264;
        const float* g1rb = G1r + b * 200;
        const float* g1ib = G1i + b * 200;
        const float* g2rb = G2r + b * 200;
        const float* g2ib = G2i + b * 200;
        const float* urb  = Ur  + b * 800;
        const float* uib  = Ui  + b * 800;

        // ---- stage theta/G/F into per-wave LDS (wide coalesced loads) ----
        // wave-local: prior iteration's LDS reads must complete before overwrite
        asm volatile("s_waitcnt lgkmcnt(0)" ::: "memory");
        __builtin_amdgcn_wave_barrier();
        if (lane < 25) {           // theta: 100 complex, interleaved (re,im)
            float4 r = ((const float4*)tb)[lane];
            float4 i = ((const float4*)(tb + 100))[lane];
            float2* d = (float2*)W + lane * 4;
            d[0] = make_float2(r.x, i.x);
            d[1] = make_float2(r.y, i.y);
            d[2] = make_float2(r.z, i.z);
            d[3] = make_float2(r.w, i.w);
        }
        if (lane < 50) {           // G1, G2: 200 complex each, interleaved
            float4 r = ((const float4*)g1rb)[lane];
            float4 i = ((const float4*)g1ib)[lane];
            float2* d = (float2*)(W + 200) + lane * 4;
            d[0] = make_float2(r.x, i.x);
            d[1] = make_float2(r.y, i.y);
            d[2] = make_float2(r.z, i.z);
            d[3] = make_float2(r.w, i.w);
            r = ((const float4*)g2rb)[lane];
            i = ((const float4*)g2ib)[lane];
            d = (float2*)(W + 600) + lane * 4;
            d[0] = make_float2(r.x, i.x);
            d[1] = make_float2(r.y, i.y);
            d[2] = make_float2(r.z, i.z);
            d[3] = make_float2(r.w, i.w);
        }
        if (lane < 16)             // F section: raw copy of tb[200..263]
            ((float4*)(W + 1000))[lane] = ((const float4*)(tb + 200))[lane];
        asm volatile("s_waitcnt lgkmcnt(0)" ::: "memory");
        __builtin_amdgcn_wave_barrier();

        // phi partials: [0,1]=phi1 n0 re/im, [2,3]=phi1 n1, [4,5]=phi2 n0, [6,7]=phi2 n1
        float p[8] = {0,0,0,0,0,0,0,0};

        #pragma unroll 1   // keep the rolled schedule (low VGPR, high occupancy)
        for (int j = 0; j < 12; ++j) {
            const int k = 8*j + k0;
            float2 th = *(const float2*)(W + 2*k);          // theta[k]
            float2 a  = *(const float2*)(W + 200 + 2*k);    // g1[0][k]
            float2 c  = *(const float2*)(W + 400 + 2*k);    // g1[1][k]
            float2 d2 = *(const float2*)(W + 600 + 2*k);    // g2[0][k]
            float2 e2 = *(const float2*)(W + 800 + 2*k);    // g2[1][k]
            float ur = urb[64*j + lane], ui = uib[64*j + lane];  // coalesced
            float wr = th.x*ur - th.y*ui, wi = th.x*ui + th.y*ur;
            p[0] += a.x*wr  - a.y*wi;   p[1] += a.x*wi  + a.y*wr;
            p[2] += c.x*wr  - c.y*wi;   p[3] += c.x*wi  + c.y*wr;
            p[4] += d2.x*wr - d2.y*wi;  p[5] += d2.x*wi + d2.y*wr;
            p[6] += e2.x*wr - e2.y*wi;  p[7] += e2.x*wi + e2.y*wr;
        }
        // tail strip: k = 96 + k0, valid only for k0 < 4 (lane < 32)
        if (k0 < 4) {
            const int k = 96 + k0;
            float2 th = *(const float2*)(W + 2*k);
            float2 a  = *(const float2*)(W + 200 + 2*k);
            float2 c  = *(const float2*)(W + 400 + 2*k);
            float2 d2 = *(const float2*)(W + 600 + 2*k);
            float2 e2 = *(const float2*)(W + 800 + 2*k);
            float ur = urb[768 + lane], ui = uib[768 + lane];
            float wr = th.x*ur - th.y*ui, wi = th.x*ui + th.y*ur;
            p[0] += a.x*wr  - a.y*wi;   p[1] += a.x*wi  + a.y*wr;
            p[2] += c.x*wr  - c.y*wi;   p[3] += c.x*wi  + c.y*wr;
            p[4] += d2.x*wr - d2.y*wi;  p[5] += d2.x*wi + d2.y*wr;
            p[6] += e2.x*wr - e2.y*wi;  p[7] += e2.x*wi + e2.y*wr;
        }

        // reduce over the 8 k-strips (lane bits 3..5): stages 8 and 32 on all 8
        // partials, then exchange-then-add on bit 4 (keep nn, send 1-nn).
        #pragma unroll
        for (int q = 0; q < 8; ++q) {
            p[q] += __shfl_xor(p[q], 8);
            p[q] += __shfl_xor(p[q], 32);
        }
        float4 ph;  // phi1[nn].re/.im, phi2[nn].re/.im (full k-sum after exchange)
        {
            float k0r = nn ? p[2] : p[0], s0r = nn ? p[0] : p[2];
            float k0i = nn ? p[3] : p[1], s0i = nn ? p[1] : p[3];
            float k1r = nn ? p[6] : p[4], s1r = nn ? p[4] : p[6];
            float k1i = nn ? p[7] : p[5], s1i = nn ? p[5] : p[7];
            ph.x = k0r + __shfl_xor(s0r, 16);
            ph.y = k0i + __shfl_xor(s0i, 16);
            ph.z = k1r + __shfl_xor(s1r, 16);
            ph.w = k1i + __shfl_xor(s1i, 16);
        }

        // ---- F norms: scale_h = sqrt(2 / sum|F_h|^2) ----  (F from LDS)
        float s1, s2;
        {
            int idx = lane & 15;
            int sel = (lane >> 4) & 1;
            float fr = W[1000 + sel*32 + idx];
            float fi = W[1016 + sel*32 + idx];
            float m = fr*fr + fi*fi;
            #pragma unroll
            for (int s = 1; s < 16; s <<= 1) m += __shfl_xor(m, s);
            float other = __shfl_xor(m, 16);
            float nrm1 = sel ? other : m;
            float nrm2 = sel ? m : other;
            s1 = sqrtf(2.0f / nrm1);
            s2 = sqrtf(2.0f / nrm2);
        }

        // ---- A/C entries: ent[it][0..7] = {A,C} for R1; [8..15] for R2 ----
        {
            int jf = t*2 + rr;
            float2 f1 = make_float2(W[1000 + jf], W[1016 + jf]);
            float2 f2 = make_float2(W[1032 + jf], W[1048 + jf]);
            float2 phi1n = make_float2(ph.x, ph.y);
            float2 phi2n = make_float2(ph.z, ph.w);
            bool lo = (e8 < 4);
            float2 E0 = cmul(phi1n, lo ? f1 : f2);
            float2 E1 = cmul(phi2n, lo ? f2 : f1);
            #pragma unroll
            for (int s = 1; s < 8; s <<= 1) {
                E0.x += __shfl_xor(E0.x, s); E0.y += __shfl_xor(E0.y, s);
                E1.x += __shfl_xor(E1.x, s); E1.y += __shfl_xor(E1.y, s);
            }
            if (t == 0) {
                ent[wave][it][e8]     = cscale(lo ? s1 : s2, E0);
                ent[wave][it][e8 + 8] = cscale(lo ? s2 : s1, E1);
            }
        }
    }
    asm volatile("s_waitcnt lgkmcnt(0)" ::: "memory");
    __builtin_amdgcn_wave_barrier();

    // ---- batched 2x2 complex rate: lanes 0..7 -> (it = lane>>1, R1/R2 = lane&1) ----
    float negR = 0.0f;
    if (lane < 8) {
        const float2* e = &ent[wave][lane >> 1][(lane & 1) * 8];
        float2 A00=e[0], A01=e[1], A10=e[2], A11=e[3];
        float2 C00=e[4], C01=e[5], C10=e[6], C11=e[7];
        float mu00 = C00.x*C00.x + C00.y*C00.y + C01.x*C01.x + C01.y*C01.y + NOISE;
        float mu11 = C10.x*C10.x + C10.y*C10.y + C11.x*C11.x + C11.y*C11.y + NOISE;
        float2 mu01 = cadd(cmulconj(C00, C10), cmulconj(C01, C11));
        mu01.x += NOISE;
        float det = mu00*mu11 - (mu01.x*mu01.x + mu01.y*mu01.y);
        float inv = 1.0f / det;
        float2 mu01c = make_float2(mu01.x, -mu01.y);
        float2 X00 = cscale(inv, csub(cscale(mu11, A00), cmul(mu01,  A10)));
        float2 X01 = cscale(inv, csub(cscale(mu11, A01), cmul(mu01,  A11)));
        float2 X10 = cscale(inv, csub(cscale(mu00, A10), cmul(mu01c, A00)));
        float2 X11 = cscale(inv, csub(cscale(mu00, A11), cmul(mu01c, A01)));
        float2 I00 = cadd(cconjmul(A00, X00), cconjmul(A10, X10));
        float2 I01 = cadd(cconjmul(A00, X01), cconjmul(A10, X11));
        float2 I10 = cadd(cconjmul(A01, X00), cconjmul(A11, X10));
        float2 I11 = cadd(cconjmul(A01, X01), cconjmul(A11, X11));
        I00.x += 1.0f; I01.x += 1.0f; I10.x += 1.0f; I11.x += 1.0f;
        float2 dT = csub(cmul(I00, I11), cmul(I01, I10));
        negR = -0.5f * logf(dT.x*dT.x + dT.y*dT.y);  // -Re(log z) = -ln|z|
    }
    // pairwise max over (R1,R2), then sum the 4 batch elements
    float m = fmaxf(negR, __shfl_xor(negR, 1));
    m += __shfl_xor(m, 2);
    m += __shfl_xor(m, 4);
    if (lane == 0) wsum[wave] = m;

    __syncthreads();
    if (threadIdx.x == 0)
        partial[blockIdx.x] = (wsum[0] + wsum[1]) + (wsum[2] + wsum[3]);
}

__global__ __launch_bounds__(256) void reduce_kernel(
    const float* __restrict__ partial, int n, float invB, float* __restrict__ out)
{
    __shared__ float sd[256];
    float s = 0.0f;
    for (int i = threadIdx.x; i < n; i += 256) s += partial[i];
    sd[threadIdx.x] = s;
    __syncthreads();
    for (int o = 128; o > 0; o >>= 1) {
        if ((int)threadIdx.x < o) sd[threadIdx.x] += sd[threadIdx.x + o];
        __syncthreads();
    }
    if (threadIdx.x == 0) out[0] = sd[0] * invB;
}

extern "C" void kernel_launch(void* const* d_in, const int* in_sizes, int n_in,
                              void* d_out, int out_size, void* d_ws, size_t ws_size,
                              hipStream_t stream) {
    const float* t1  = (const float*)d_in[0];
    const float* G1r = (const float*)d_in[1];
    const float* G1i = (const float*)d_in[2];
    const float* G2r = (const float*)d_in[3];
    const float* G2i = (const float*)d_in[4];
    const float* Ur  = (const float*)d_in[5];
    const float* Ui  = (const float*)d_in[6];

    const int B = in_sizes[0] / 264;        // 65536
    const int nblocks = B / 16;             // 16 batch elements per block
    float* partial = (float*)d_ws;          // nblocks floats

    rate_kernel<<<nblocks, 256, 0, stream>>>(t1, G1r, G1i, G2r, G2i, Ur, Ui, partial);
    reduce_kernel<<<1, 256, 0, stream>>>(partial, nblocks, 1.0f / (float)B, (float*)d_out);
}

// Round 7
// 145.394 us; speedup vs baseline: 2.7663x; 1.1401x over previous
//
#include <hip/hip_runtime.h>
#include <math.h>

#define NOISE 1e-12f
#define WSZ 1064   // per-wave LDS floats: theta(200) | G1(400) | G2(400) | F(64)

__device__ __forceinline__ float2 cmul(float2 a, float2 b) {
    return make_float2(a.x*b.x - a.y*b.y, a.x*b.y + a.y*b.x);
}
// conj(a)*b
__device__ __forceinline__ float2 cconjmul(float2 a, float2 b) {
    return make_float2(a.x*b.x + a.y*b.y, a.x*b.y - a.y*b.x);
}
// a*conj(b)
__device__ __forceinline__ float2 cmulconj(float2 a, float2 b) {
    return make_float2(a.x*b.x + a.y*b.y, a.y*b.x - a.x*b.y);
}
__device__ __forceinline__ float2 cadd(float2 a, float2 b){ return make_float2(a.x+b.x, a.y+b.y); }
__device__ __forceinline__ float2 csub(float2 a, float2 b){ return make_float2(a.x-b.x, a.y-b.y); }
__device__ __forceinline__ float2 cscale(float s, float2 a){ return make_float2(s*a.x, s*a.y); }

// one wave per batch element iteration; 4 waves/block; 4 iterations -> 16 b per block
__global__ __launch_bounds__(256) void rate_kernel(
    const float* __restrict__ t1,
    const float* __restrict__ G1r, const float* __restrict__ G1i,
    const float* __restrict__ G2r, const float* __restrict__ G2i,
    const float* __restrict__ Ur,  const float* __restrict__ Ui,
    float* __restrict__ partial)
{
    __shared__ float lds[4 * WSZ];     // per-wave staging buffers
    __shared__ float2 ent[4][4][16];   // [wave][it][entry]
    __shared__ float wsum[4];
    const int wave = threadIdx.x >> 6;
    const int lane = threadIdx.x & 63;
    const int t  = lane & 7;     // output column of phi
    const int k0 = lane >> 3;    // k-strip (k = 8j + k0), reused as entry-octet id
    const int e8 = k0;
    const int nn = (e8 >> 1) & 1;   // = lane bit 4
    const int rr = e8 & 1;
    float* W = lds + wave * WSZ;

    for (int it = 0; it < 4; ++it) {
        const long b = (long)blockIdx.x * 16 + (long)wave * 4 + it;
        const float* tb   = t1  + b * 264;
        const float* g1rb = G1r + b * 200;
        const float* g1ib = G1i + b * 200;
        const float* g2rb = G2r + b * 200;
        const float* g2ib = G2i + b * 200;
        const float* urb  = Ur  + b * 800;
        const float* uib  = Ui  + b * 800;

        // ---- stage theta/G/F into per-wave LDS (wide coalesced loads) ----
        // wave-local: prior iteration's LDS reads must complete before overwrite
        asm volatile("s_waitcnt lgkmcnt(0)" ::: "memory");
        __builtin_amdgcn_wave_barrier();
        if (lane < 25) {           // theta: 100 complex, interleaved (re,im)
            float4 r = ((const float4*)tb)[lane];
            float4 i = ((const float4*)(tb + 100))[lane];
            float2* d = (float2*)W + lane * 4;
            d[0] = make_float2(r.x, i.x);
            d[1] = make_float2(r.y, i.y);
            d[2] = make_float2(r.z, i.z);
            d[3] = make_float2(r.w, i.w);
        }
        if (lane < 50) {           // G1, G2: 200 complex each, interleaved
            float4 r = ((const float4*)g1rb)[lane];
            float4 i = ((const float4*)g1ib)[lane];
            float2* d = (float2*)(W + 200) + lane * 4;
            d[0] = make_float2(r.x, i.x);
            d[1] = make_float2(r.y, i.y);
            d[2] = make_float2(r.z, i.z);
            d[3] = make_float2(r.w, i.w);
            r = ((const float4*)g2rb)[lane];
            i = ((const float4*)g2ib)[lane];
            d = (float2*)(W + 600) + lane * 4;
            d[0] = make_float2(r.x, i.x);
            d[1] = make_float2(r.y, i.y);
            d[2] = make_float2(r.z, i.z);
            d[3] = make_float2(r.w, i.w);
        }
        if (lane < 16)             // F section: raw copy of tb[200..263]
            ((float4*)(W + 1000))[lane] = ((const float4*)(tb + 200))[lane];
        asm volatile("s_waitcnt lgkmcnt(0)" ::: "memory");
        __builtin_amdgcn_wave_barrier();

        // phi partials: [0,1]=phi1 n0 re/im, [2,3]=phi1 n1, [4,5]=phi2 n0, [6,7]=phi2 n1
        float p[8] = {0,0,0,0,0,0,0,0};

        // U stream, 4-deep register prefetch (issue-early / use-late).
        // Strip s: U flat index 64s+lane (coalesced); strip 12 clamped+masked.
        #define LDU(s) make_float2(urb[(s)*64 + lane], uib[(s)*64 + lane])
        // compute body for strip s with prefetched u
        #define CBODY(k, u) {                                        \
            float2 th = *(const float2*)(W + 2*(k));                 \
            float2 a  = *(const float2*)(W + 200 + 2*(k));           \
            float2 c  = *(const float2*)(W + 400 + 2*(k));           \
            float2 d2 = *(const float2*)(W + 600 + 2*(k));           \
            float2 e2 = *(const float2*)(W + 800 + 2*(k));           \
            float wr = th.x*(u).x - th.y*(u).y;                      \
            float wi = th.x*(u).y + th.y*(u).x;                      \
            p[0] += a.x*wr  - a.y*wi;   p[1] += a.x*wi  + a.y*wr;    \
            p[2] += c.x*wr  - c.y*wi;   p[3] += c.x*wi  + c.y*wr;    \
            p[4] += d2.x*wr - d2.y*wi;  p[5] += d2.x*wi + d2.y*wr;   \
            p[6] += e2.x*wr - e2.y*wi;  p[7] += e2.x*wi + e2.y*wr; }

        float2 u0 = LDU(0), u1 = LDU(1), u2 = LDU(2), u3 = LDU(3);
        const int ctail = 768 + (lane < 32 ? lane : 31);  // clamped tail offset
        #pragma unroll 1   // rolled: keep VGPR low; prefetch provides the ILP
        for (int g = 0; g < 3; ++g) {
            const int s = 4 * g;
            // issue next group's loads first (4 strips ahead of use)
            float2 n0, n1, n2, n3;
            if (g < 2) {
                n0 = LDU(s + 4); n1 = LDU(s + 5);
                n2 = LDU(s + 6); n3 = LDU(s + 7);
            } else {
                n0 = make_float2(urb[ctail], uib[ctail]);  // strip 12 (masked later)
                n1 = n2 = n3 = n0;
            }
            // compute current group from prefetched registers
            CBODY(8*s + k0,      u0);
            CBODY(8*s + 8 + k0,  u1);
            CBODY(8*s + 16 + k0, u2);
            CBODY(8*s + 24 + k0, u3);
            u0 = n0; u1 = n1; u2 = n2; u3 = n3;
        }
        // tail strip 12: k = 96 + k0, valid only k0 < 4 (u0 holds clamped load)
        if (k0 < 4) {
            CBODY(96 + k0, u0);
        }
        #undef LDU
        #undef CBODY

        // reduce over the 8 k-strips (lane bits 3..5): stages 8 and 32 on all 8
        // partials, then exchange-then-add on bit 4 (keep nn, send 1-nn).
        #pragma unroll
        for (int q = 0; q < 8; ++q) {
            p[q] += __shfl_xor(p[q], 8);
            p[q] += __shfl_xor(p[q], 32);
        }
        float4 ph;  // phi1[nn].re/.im, phi2[nn].re/.im (full k-sum after exchange)
        {
            float k0r = nn ? p[2] : p[0], s0r = nn ? p[0] : p[2];
            float k0i = nn ? p[3] : p[1], s0i = nn ? p[1] : p[3];
            float k1r = nn ? p[6] : p[4], s1r = nn ? p[4] : p[6];
            float k1i = nn ? p[7] : p[5], s1i = nn ? p[5] : p[7];
            ph.x = k0r + __shfl_xor(s0r, 16);
            ph.y = k0i + __shfl_xor(s0i, 16);
            ph.z = k1r + __shfl_xor(s1r, 16);
            ph.w = k1i + __shfl_xor(s1i, 16);
        }

        // ---- F norms: scale_h = sqrt(2 / sum|F_h|^2) ----  (F from LDS)
        float s1, s2;
        {
            int idx = lane & 15;
            int sel = (lane >> 4) & 1;
            float fr = W[1000 + sel*32 + idx];
            float fi = W[1016 + sel*32 + idx];
            float m = fr*fr + fi*fi;
            #pragma unroll
            for (int s = 1; s < 16; s <<= 1) m += __shfl_xor(m, s);
            float other = __shfl_xor(m, 16);
            float nrm1 = sel ? other : m;
            float nrm2 = sel ? m : other;
            s1 = sqrtf(2.0f / nrm1);
            s2 = sqrtf(2.0f / nrm2);
        }

        // ---- A/C entries: ent[it][0..7] = {A,C} for R1; [8..15] for R2 ----
        {
            int jf = t*2 + rr;
            float2 f1 = make_float2(W[1000 + jf], W[1016 + jf]);
            float2 f2 = make_float2(W[1032 + jf], W[1048 + jf]);
            float2 phi1n = make_float2(ph.x, ph.y);
            float2 phi2n = make_float2(ph.z, ph.w);
            bool lo = (e8 < 4);
            float2 E0 = cmul(phi1n, lo ? f1 : f2);
            float2 E1 = cmul(phi2n, lo ? f2 : f1);
            #pragma unroll
            for (int s = 1; s < 8; s <<= 1) {
                E0.x += __shfl_xor(E0.x, s); E0.y += __shfl_xor(E0.y, s);
                E1.x += __shfl_xor(E1.x, s); E1.y += __shfl_xor(E1.y, s);
            }
            if (t == 0) {
                ent[wave][it][e8]     = cscale(lo ? s1 : s2, E0);
                ent[wave][it][e8 + 8] = cscale(lo ? s2 : s1, E1);
            }
        }
    }
    asm volatile("s_waitcnt lgkmcnt(0)" ::: "memory");
    __builtin_amdgcn_wave_barrier();

    // ---- batched 2x2 complex rate: lanes 0..7 -> (it = lane>>1, R1/R2 = lane&1) ----
    float negR = 0.0f;
    if (lane < 8) {
        const float2* e = &ent[wave][lane >> 1][(lane & 1) * 8];
        float2 A00=e[0], A01=e[1], A10=e[2], A11=e[3];
        float2 C00=e[4], C01=e[5], C10=e[6], C11=e[7];
        float mu00 = C00.x*C00.x + C00.y*C00.y + C01.x*C01.x + C01.y*C01.y + NOISE;
        float mu11 = C10.x*C10.x + C10.y*C10.y + C11.x*C11.x + C11.y*C11.y + NOISE;
        float2 mu01 = cadd(cmulconj(C00, C10), cmulconj(C01, C11));
        mu01.x += NOISE;
        float det = mu00*mu11 - (mu01.x*mu01.x + mu01.y*mu01.y);
        float inv = 1.0f / det;
        float2 mu01c = make_float2(mu01.x, -mu01.y);
        float2 X00 = cscale(inv, csub(cscale(mu11, A00), cmul(mu01,  A10)));
        float2 X01 = cscale(inv, csub(cscale(mu11, A01), cmul(mu01,  A11)));
        float2 X10 = cscale(inv, csub(cscale(mu00, A10), cmul(mu01c, A00)));
        float2 X11 = cscale(inv, csub(cscale(mu00, A11), cmul(mu01c, A01)));
        float2 I00 = cadd(cconjmul(A00, X00), cconjmul(A10, X10));
        float2 I01 = cadd(cconjmul(A00, X01), cconjmul(A10, X11));
        float2 I10 = cadd(cconjmul(A01, X00), cconjmul(A11, X10));
        float2 I11 = cadd(cconjmul(A01, X01), cconjmul(A11, X11));
        I00.x += 1.0f; I01.x += 1.0f; I10.x += 1.0f; I11.x += 1.0f;
        float2 dT = csub(cmul(I00, I11), cmul(I01, I10));
        negR = -0.5f * logf(dT.x*dT.x + dT.y*dT.y);  // -Re(log z) = -ln|z|
    }
    // pairwise max over (R1,R2), then sum the 4 batch elements
    float m = fmaxf(negR, __shfl_xor(negR, 1));
    m += __shfl_xor(m, 2);
    m += __shfl_xor(m, 4);
    if (lane == 0) wsum[wave] = m;

    __syncthreads();
    if (threadIdx.x == 0)
        partial[blockIdx.x] = (wsum[0] + wsum[1]) + (wsum[2] + wsum[3]);
}

__global__ __launch_bounds__(256) void reduce_kernel(
    const float* __restrict__ partial, int n, float invB, float* __restrict__ out)
{
    __shared__ float sd[256];
    float s = 0.0f;
    for (int i = threadIdx.x; i < n; i += 256) s += partial[i];
    sd[threadIdx.x] = s;
    __syncthreads();
    for (int o = 128; o > 0; o >>= 1) {
        if ((int)threadIdx.x < o) sd[threadIdx.x] += sd[threadIdx.x + o];
        __syncthreads();
    }
    if (threadIdx.x == 0) out[0] = sd[0] * invB;
}

extern "C" void kernel_launch(void* const* d_in, const int* in_sizes, int n_in,
                              void* d_out, int out_size, void* d_ws, size_t ws_size,
                              hipStream_t stream) {
    const float* t1  = (const float*)d_in[0];
    const float* G1r = (const float*)d_in[1];
    const float* G1i = (const float*)d_in[2];
    const float* G2r = (const float*)d_in[3];
    const float* G2i = (const float*)d_in[4];
    const float* Ur  = (const float*)d_in[5];
    const float* Ui  = (const float*)d_in[6];

    const int B = in_sizes[0] / 264;        // 65536
    const int nblocks = B / 16;             // 16 batch elements per block
    float* partial = (float*)d_ws;          // nblocks floats

    rate_kernel<<<nblocks, 256, 0, stream>>>(t1, G1r, G1i, G2r, G2i, Ur, Ui, partial);
    reduce_kernel<<<1, 256, 0, stream>>>(partial, nblocks, 1.0f / (float)B, (float*)d_out);
}